// Round 7
// baseline (353.746 us; speedup 1.0000x reference)
//
#include <hip/hip_runtime.h>

// DIAGNOSTIC ROUND: read ALL 128 rows with arithmetic mask (no va-skip).
// Purpose: Delta(dur_us) vs round 4 measures the kernel's achieved HBM BW:
//   +133 MB reads => Delta ~ +20 us if ~6.6 TB/s (va-skip kernel was at roofline)
//                     Delta ~ +80 us if ~1.7 TB/s (structural deficit to find)
// Branch-free mask-multiply so loads cannot be elided (0*v not removable w/o fast-math).

#define BATCH     4096
#define MAX_ATOMS 128
#define N_FEAT    128
#define ROW_F4    (N_FEAT / 4)   // 32 float4 per row

__global__ __launch_bounds__(256, 8) void graph_gather_mol(
    const float* __restrict__ nf,   // [BATCH][MAX_ATOMS][N_FEAT]
    const int*   __restrict__ ds,   // [BATCH][2] = {valid_atoms, valid_feats}
    float*       __restrict__ out)  // [BATCH][N_FEAT]
{
    const int b  = blockIdx.x;
    const int t  = threadIdx.x;
    const int va = ds[b * 2 + 0];   // 1..128
    const int vf = ds[b * 2 + 1];   // 1..128

    const int f4 = t & 31;
    const int rg = t >> 5;          // 0..7

    const float4* base = reinterpret_cast<const float4*>(nf)
                       + (size_t)b * (MAX_ATOMS * ROW_F4) + f4;

    float4 a0 = make_float4(0.f, 0.f, 0.f, 0.f);
    float4 a1 = make_float4(0.f, 0.f, 0.f, 0.f);
    float4 a2 = make_float4(0.f, 0.f, 0.f, 0.f);
    float4 a3 = make_float4(0.f, 0.f, 0.f, 0.f);

    // Fixed trip count: 16 rows/thread (stride 8), fully unrolled, mask-multiply.
    #pragma unroll
    for (int i = 0; i < 4; ++i) {
        const int r0 = rg + (i * 4 + 0) * 8;
        const int r1 = rg + (i * 4 + 1) * 8;
        const int r2 = rg + (i * 4 + 2) * 8;
        const int r3 = rg + (i * 4 + 3) * 8;
        float4 v0 = base[(size_t)r0 * ROW_F4];
        float4 v1 = base[(size_t)r1 * ROW_F4];
        float4 v2 = base[(size_t)r2 * ROW_F4];
        float4 v3 = base[(size_t)r3 * ROW_F4];
        const float m0 = (r0 < va) ? 1.f : 0.f;
        const float m1 = (r1 < va) ? 1.f : 0.f;
        const float m2 = (r2 < va) ? 1.f : 0.f;
        const float m3 = (r3 < va) ? 1.f : 0.f;
        a0.x = fmaf(m0, v0.x, a0.x); a0.y = fmaf(m0, v0.y, a0.y);
        a0.z = fmaf(m0, v0.z, a0.z); a0.w = fmaf(m0, v0.w, a0.w);
        a1.x = fmaf(m1, v1.x, a1.x); a1.y = fmaf(m1, v1.y, a1.y);
        a1.z = fmaf(m1, v1.z, a1.z); a1.w = fmaf(m1, v1.w, a1.w);
        a2.x = fmaf(m2, v2.x, a2.x); a2.y = fmaf(m2, v2.y, a2.y);
        a2.z = fmaf(m2, v2.z, a2.z); a2.w = fmaf(m2, v2.w, a2.w);
        a3.x = fmaf(m3, v3.x, a3.x); a3.y = fmaf(m3, v3.y, a3.y);
        a3.z = fmaf(m3, v3.z, a3.z); a3.w = fmaf(m3, v3.w, a3.w);
    }
    a0.x += a1.x + a2.x + a3.x;
    a0.y += a1.y + a2.y + a3.y;
    a0.z += a1.z + a2.z + a3.z;
    a0.w += a1.w + a2.w + a3.w;

    __shared__ float4 red[256];
    red[t] = a0;
    __syncthreads();

    if (t < 32) {
        float4 s = red[t];
        #pragma unroll
        for (int g = 1; g < 8; ++g) {
            float4 v = red[g * 32 + t];
            s.x += v.x; s.y += v.y; s.z += v.z; s.w += v.w;
        }
        const int f0 = t * 4;
        s.x = (f0 + 0 < vf) ? fmaxf(s.x, 0.f) : 0.f;
        s.y = (f0 + 1 < vf) ? fmaxf(s.y, 0.f) : 0.f;
        s.z = (f0 + 2 < vf) ? fmaxf(s.z, 0.f) : 0.f;
        s.w = (f0 + 3 < vf) ? fmaxf(s.w, 0.f) : 0.f;
        reinterpret_cast<float4*>(out)[b * ROW_F4 + t] = s;
    }
}

extern "C" void kernel_launch(void* const* d_in, const int* in_sizes, int n_in,
                              void* d_out, int out_size, void* d_ws, size_t ws_size,
                              hipStream_t stream) {
    const float* nf  = (const float*)d_in[0];
    const int*   ds  = (const int*)d_in[1];
    float*       out = (float*)d_out;
    graph_gather_mol<<<BATCH, 256, 0, stream>>>(nf, ds, out);
}